// Round 18
// baseline (777.177 us; speedup 1.0000x reference)
//
#include <hip/hip_runtime.h>

#define DEVI __device__ __forceinline__

typedef __attribute__((ext_vector_type(8))) __bf16 bf16x8;
typedef __attribute__((ext_vector_type(16))) float floatx16;

constexpr int Bsz = 8192;   // batch
constexpr int Hd  = 2048;   // hidden
constexpr int INd = 2048;   // input dim
constexpr int N1  = Bsz * INd;

DEVI unsigned short f2bf_rne(float f) {
  unsigned int u = __float_as_uint(f);
  u += 0x7FFFu + ((u >> 16) & 1u);
  return (unsigned short)(u >> 16);
}

__global__ void cvt4(const float* __restrict__ s0, const float* __restrict__ s1,
                     const float* __restrict__ s2, const float* __restrict__ s3,
                     unsigned short* __restrict__ dst) {
  const float* src = (blockIdx.y == 0) ? s0 : (blockIdx.y == 1) ? s1
                   : (blockIdx.y == 2) ? s2 : s3;
  unsigned short* out = dst + (size_t)blockIdx.y * N1;
  const int nv = N1 / 4;
  for (int i = blockIdx.x * blockDim.x + threadIdx.x; i < nv;
       i += gridDim.x * blockDim.x) {
    float4 v = ((const float4*)src)[i];
    ushort4 o;
    o.x = f2bf_rne(v.x); o.y = f2bf_rne(v.y);
    o.z = f2bf_rne(v.z); o.w = f2bf_rne(v.w);
    ((ushort4*)out)[i] = o;
  }
}

DEVI void gload_lds16(const void* g, void* l) {
  __builtin_amdgcn_global_load_lds(
      (const __attribute__((address_space(1))) void*)g,
      (__attribute__((address_space(3))) void*)l, 16, 0, 0);
}

DEVI float sigm(float x) { return 1.0f / (1.0f + __expf(-x)); }
DEVI float tanh_fast(float x) { return 1.0f - 2.0f / (1.0f + __expf(2.0f * x)); }

// R18: 256(batch) x 256(weight) tile, BK=64, SIXTEEN waves (4 weight-M "ww"
// x 4 batch-N "wb"), 32x32x16 MFMA (2495 TF ceiling, -17% MFMA floor vs
// 16x16x32), TRANSPOSED mfma(W,X): C row = weight (reg), col = batch (lane).
// Weight-row layout (R13-verified): LDS W-row wr -> weight row
// gate*2048 + bc*64 + (wr>>5)*8 + (wr&7), gate=(wr>>3)&3 => acc reg
// gate*4+q, gate lane-local, float4 epilogue stores.
// COLUMN-MAJOR LDS (R13-verified, 0 conflicts): byte = k8*4096 + row*16;
// 32-lane fragment read = 512 consecutive bytes. Staging fills one
// (k8=wid&7, 64-row) strip per gload (linear dest).
// Per wave per K-tile(64): 16 ds_read_b128, 16 MFMA, 4 gloads; acc = 64
// regs (2x2 floatx16), frag peak-live 48 VGPR (ring holds).
// Schedule/ledger = R17 (2 barriers, depth-2 vmcnt(2)): ring
// (0,0)(0,1)(1,1)(1,0); ph1 stage W(t+1)->P^1 (W-P^1 last read pre t-1
// end-BAR); ph3 stage X(t+2)->P (X-P last read ph2, behind mid-BAR);
// ph4 vmcnt(2) confirms X(t+1)+W(t+1), leaves X(t+2) flying.
__global__ __launch_bounds__(1024, 4) void lstm_gemm(
    const unsigned short* __restrict__ ws,
    const float* __restrict__ bias,
    const float* __restrict__ c_prev,
    float* __restrict__ out_h,
    float* __restrict__ out_c) {
  __shared__ __align__(16) unsigned short sm[4 * 256 * 64];  // 128 KiB
  char* smc = (char*)sm;

  const unsigned short* xb  = ws;
  const unsigned short* hb  = ws + (size_t)N1;
  const unsigned short* wih = ws + (size_t)2 * N1;
  const unsigned short* whh = ws + (size_t)3 * N1;

  const int tid  = threadIdx.x;
  const int lane = tid & 63;
  const int wid  = tid >> 6;    // 0..15
  const int ww   = wid >> 2;    // weight wave 0..3 (64 weight rows)
  const int wb   = wid & 3;     // batch wave 0..3 (64 batch cols)
  const int l31  = lane & 31, l5 = lane >> 5;

  // XCD-aware chunked swizzle (FETCH 1.1GB -> 427MB). 1024 blocks.
  const int wg = blockIdx.x;
  const int x8 = wg & 7;
  const int lc = wg >> 3;
  const int bc = (x8 & 3) * 8 + (lc & 7);             // h-panel 0..31 (64 h)
  const int rb = ((x8 >> 2) * 16 + (lc >> 3)) * 256;  // batch row base

  // Staging source offsets (elements). Wave wid owns k8-column (wid&7) and
  // row-half (wid>>3); gload j covers rows (wid>>3)*128 + j*64 + lane.
  const int k8c = wid & 7;            // K-chunk column 0..7
  const int rh  = wid >> 3;           // row-half 0..1
  unsigned int aOff[2], bOff[2];
#pragma unroll
  for (int j = 0; j < 2; ++j) {
    const int r = rh * 128 + j * 64 + lane;   // LDS row 0..255
    aOff[j] = (unsigned)(rb + r) * 2048u + (unsigned)(k8c * 8);
    const int wrow = ((r >> 3) & 3) * 2048 + bc * 64 + (r >> 5) * 8 + (r & 7);
    bOff[j] = (unsigned)wrow * 2048u + (unsigned)(k8c * 8);
  }

  // Per-lane LDS read bases (column-major). X in first half of each buf's
  // 32KB block, W at +65536. k8 = ks*2 + l5 -> l5*4096 in base, ks*8192 in
  // compile-time offset (max 512 + 24576 = 25088 < 65536).
  const char* pX[2];
  const char* pW[2];
#pragma unroll
  for (int p = 0; p < 2; ++p) {
    pX[p] = smc + p * 32768 + wb * 1024 + l31 * 16 + l5 * 4096;
    pW[p] = smc + 65536 + p * 32768 + ww * 1024 + l31 * 16 + l5 * 4096;
  }

  floatx16 acc[2][2];  // [mw][qx]
#pragma unroll
  for (int a = 0; a < 2; ++a)
#pragma unroll
    for (int b = 0; b < 2; ++b)
#pragma unroll
      for (int e = 0; e < 16; ++e) acc[a][b][e] = 0.f;

#define STAGE_X(ts) {                                                         \
    const int p_ = (ts) & 1;                                                  \
    const unsigned short* s_ = (((ts) < 32) ? xb : hb) + (((ts) & 31) * 64);  \
    gload_lds16(s_ + aOff[0], smc + p_ * 32768 + k8c * 4096 + rh * 2048);     \
    gload_lds16(s_ + aOff[1], smc + p_ * 32768 + k8c * 4096 + rh * 2048 + 1024); }
#define STAGE_W(ts) {                                                         \
    const int p_ = (ts) & 1;                                                  \
    const unsigned short* s_ = (((ts) < 32) ? wih : whh) + (((ts) & 31) * 64);\
    gload_lds16(s_ + bOff[0], smc + 65536 + p_ * 32768 + k8c * 4096 + rh * 2048);     \
    gload_lds16(s_ + bOff[1], smc + 65536 + p_ * 32768 + k8c * 4096 + rh * 2048 + 1024); }

// Fragment reads: base + compile-time offset. W row = ww*64 + MW*32 + l31;
// X row = wb*64 + QX*32 + l31.
#define LDW(D, P, MW)                                                         \
  _Pragma("unroll") for (int ks = 0; ks < 4; ++ks)                            \
    D[ks] = *(const bf16x8*)(pW[P] + ((MW) * 512 + ks * 8192));
#define LDX(D, P, QX)                                                         \
  _Pragma("unroll") for (int ks = 0; ks < 4; ++ks)                            \
    D[ks] = *(const bf16x8*)(pX[P] + ((QX) * 512 + ks * 8192));
#define MM(MW, QX, WF, XF)                                                    \
  __builtin_amdgcn_s_setprio(1);                                              \
  _Pragma("unroll") for (int ks = 0; ks < 4; ++ks)                            \
    acc[MW][QX] = __builtin_amdgcn_mfma_f32_32x32x16_bf16(                    \
        WF[ks], XF[ks], acc[MW][QX], 0, 0, 0);                                \
  __builtin_amdgcn_s_setprio(0);
#define BAR  asm volatile("s_barrier" ::: "memory")
#define VM2  asm volatile("s_waitcnt vmcnt(2)" ::: "memory")
#define VM0  asm volatile("s_waitcnt vmcnt(0)" ::: "memory")
#define NOP  (void)0

// One K-tile(64), buf P, ring (mw,qx) = (0,0)(0,1)(1,1)(1,0), 2 barriers.
// Reads: ph1 wf0(4)+x0(4); ph2 x1(4); ph3 wf1(4); ph4 none (x0 held).
#define KTILE(P, S1, S3, W) {                                                 \
    bf16x8 wf0[4], wf1[4], x0[4], x1[4];                                      \
    LDW(wf0, P, 0); LDX(x0, P, 0); S1;                                        \
    MM(0, 0, wf0, x0);                                                        \
    LDX(x1, P, 1);                                                            \
    MM(0, 1, wf0, x1); BAR;                                                   \
    LDW(wf1, P, 1); S3;                                                       \
    MM(1, 1, wf1, x1);                                                        \
    MM(1, 0, wf1, x0); W; BAR;                                                \
  }

  // Prologue: X(0), W(0), X(1); confirm first four; barrier.
  STAGE_X(0); STAGE_W(0); STAGE_X(1);
  VM2;
  BAR;

  // 64 K-tiles of 64 (32 x/W_ih + 32 h/W_hh), unrolled x2.
  for (int u = 0; u < 31; ++u) {
    const int t0 = 2 * u;
    KTILE(0, STAGE_W(t0 + 1), STAGE_X(t0 + 2), VM2);
    KTILE(1, STAGE_W(t0 + 2), STAGE_X(t0 + 3), VM2);
  }
  KTILE(0, STAGE_W(63), NOP, VM0);  // t = 62: last W; full drain
  KTILE(1, NOP, NOP, NOP);          // t = 63

  // Epilogue (R13-verified): gate = reg>>2 lane-local, float4 ld/st.
#pragma unroll
  for (int mw = 0; mw < 2; ++mw) {
    const int hb4 = bc * 64 + (ww * 2 + mw) * 8 + l5 * 4;
    const float4 bi4 = *(const float4*)&bias[hb4];
    const float4 bf4 = *(const float4*)&bias[2048 + hb4];
    const float4 bj4 = *(const float4*)&bias[4096 + hb4];
    const float4 bo4 = *(const float4*)&bias[6144 + hb4];
#pragma unroll
    for (int qx = 0; qx < 2; ++qx) {
      const int brow = rb + wb * 64 + qx * 32 + l31;
      const size_t base = (size_t)brow * 2048 + hb4;
      const float4 cp = *(const float4*)&c_prev[base];
      float4 hv, cv;
#pragma unroll
      for (int q = 0; q < 4; ++q) {
        const float gi = acc[mw][qx][q]      + ((const float*)&bi4)[q];
        const float gf = acc[mw][qx][4 + q]  + ((const float*)&bf4)[q];
        const float gj = acc[mw][qx][8 + q]  + ((const float*)&bj4)[q];
        const float go = acc[mw][qx][12 + q] + ((const float*)&bo4)[q];
        const float iv = sigm(gi);
        const float fv = sigm(gf);
        const float jv = tanh_fast(gj);
        const float ov = sigm(go);
        const float cq = fv * ((const float*)&cp)[q] + fminf(1.0f - fv, iv) * jv;
        ((float*)&cv)[q] = cq;
        ((float*)&hv)[q] = ov * tanh_fast(cq);
      }
      *(float4*)&out_h[base] = hv;
      *(float4*)&out_c[base] = cv;
    }
  }
}

extern "C" void kernel_launch(void* const* d_in, const int* in_sizes, int n_in,
                              void* d_out, int out_size, void* d_ws, size_t ws_size,
                              hipStream_t stream) {
  const float* x      = (const float*)d_in[0];
  const float* h_prev = (const float*)d_in[1];
  const float* c_prev = (const float*)d_in[2];
  const float* w_ih   = (const float*)d_in[3];
  const float* w_hh   = (const float*)d_in[4];
  const float* bias   = (const float*)d_in[5];

  float* out_h = (float*)d_out;
  float* out_c = out_h + (size_t)Bsz * Hd;
  unsigned short* wsb = (unsigned short*)d_ws;

  dim3 cgrid(2048, 4);
  cvt4<<<cgrid, 256, 0, stream>>>(x, h_prev, w_ih, w_hh, wsb);

  // 32 row-panels x 32 col-panels = 1024 blocks, 1024 threads (16 waves).
  lstm_gemm<<<1024, 1024, 0, stream>>>(wsb, bias, c_prev, out_h, out_c);
}